// Round 1
// baseline (1180.232 us; speedup 1.0000x reference)
//
#include <hip/hip_runtime.h>
#include <math.h>

#define EPS_F 1e-6f

__device__ __forceinline__ float wave_sum64(float v){
  #pragma unroll
  for (int m = 32; m > 0; m >>= 1) v += __shfl_xor(v, m, 64);
  return v;
}

__device__ __forceinline__ float dot4(float4 a, float4 b){
  return a.x*b.x + a.y*b.y + a.z*b.z + a.w*b.w;
}

// Stage a 64x64 block of weights (row-major, given row stride) into LDS
// transposed with pad: s[d*65 + k] = W[k*stride + d].  256 threads.
__device__ __forceinline__ void stage64(const float* __restrict__ W, int row_stride,
                                        float* __restrict__ s, int tid){
  #pragma unroll
  for (int i = 0; i < 4; ++i){
    int g4 = tid + i * 256;          // 0..1023 float4s over 4096 elems
    int kk = g4 >> 4;
    int dd = (g4 & 15) * 4;
    float4 v = *reinterpret_cast<const float4*>(W + kk * row_stride + dd);
    s[(dd + 0) * 65 + kk] = v.x;
    s[(dd + 1) * 65 + kk] = v.y;
    s[(dd + 2) * 65 + kk] = v.z;
    s[(dd + 3) * 65 + kk] = v.w;
  }
}

// Complex projection for 4 rows: orr + i*oii = (x + i*y) @ (W0 + i*W1)^T, col k
__device__ __forceinline__ void cproj4(const float* __restrict__ sx, const float* __restrict__ sy,
                                       const float* __restrict__ w0, const float* __restrict__ w1,
                                       int g, int k, float orr[4], float oii[4]){
  #pragma unroll
  for (int j = 0; j < 4; ++j){ orr[j] = 0.f; oii[j] = 0.f; }
  #pragma unroll 4
  for (int d = 0; d < 64; ++d){
    float a = w0[d*65 + k], b = w1[d*65 + k];
    #pragma unroll
    for (int j = 0; j < 4; ++j){
      float xr = sx[(g*4+j)*68 + d];
      float xi = sy[(g*4+j)*68 + d];
      orr[j] = fmaf(xr, a, orr[j]);
      orr[j] = fmaf(-xi, b, orr[j]);
      oii[j] = fmaf(xi, a, oii[j]);
      oii[j] = fmaf(xr, b, oii[j]);
    }
  }
}

#define RA 16   // rows per block in prep kernel

__global__ __launch_bounds__(256, 1) void prep_kernel(
    const float* __restrict__ z_real, const float* __restrict__ z_imag,
    const float* __restrict__ gate_W, const float* __restrict__ gate_b,
    const float* __restrict__ exp_Wr, const float* __restrict__ exp_Wi,
    const float* __restrict__ ln_scale, const float* __restrict__ ln_shift,
    const float* __restrict__ mod_bias,
    const float* __restrict__ q_Wr, const float* __restrict__ q_Wi,
    const float* __restrict__ k_Wr, const float* __restrict__ k_Wi,
    const float* __restrict__ v_Wr, const float* __restrict__ v_Wi,
    const float* __restrict__ ctx_W, const float* __restrict__ ctx_b,
    const float* __restrict__ res_W, const float* __restrict__ res_b,
    float* __restrict__ qf, float* __restrict__ kf, float* __restrict__ vf,
    float* __restrict__ resb)
{
  const int tid = threadIdx.x;
  const int k   = tid & 63;        // output column
  const int g   = tid >> 6;        // wave id 0..3; handles rows g*4..g*4+3
  const int row0 = blockIdx.x * RA;

  __shared__ float s_zr[RA * 68];
  __shared__ float s_zi[RA * 68];
  __shared__ float s_ar[RA * 68];
  __shared__ float s_ai[RA * 68];
  __shared__ float s_cw[RA * 132];
  __shared__ float s_gw[RA][4];
  __shared__ float s_w0[64 * 65];
  __shared__ float s_w1[64 * 65];

  { // stage z rows (16 rows x 64), padded stride 68 (16B aligned)
    int r  = tid >> 4;
    int dd = (tid & 15) * 4;
    float4 a = *reinterpret_cast<const float4*>(z_real + (size_t)(row0 + r) * 64 + dd);
    float4 b = *reinterpret_cast<const float4*>(z_imag + (size_t)(row0 + r) * 64 + dd);
    *reinterpret_cast<float4*>(s_zr + r * 68 + dd) = a;
    *reinterpret_cast<float4*>(s_zi + r * 68 + dd) = b;
  }
  __syncthreads();

  { // gate logits + softmax (each thread redundantly does row r = tid>>4)
    int r = tid >> 4;
    float lg[4];
    #pragma unroll
    for (int e = 0; e < 4; ++e){
      float acc = gate_b[e];
      #pragma unroll 8
      for (int d = 0; d < 64; ++d)
        acc += s_zr[r*68 + d] * gate_W[e*128 + d] + s_zi[r*68 + d] * gate_W[e*128 + 64 + d];
      lg[e] = acc;
    }
    float mx = fmaxf(fmaxf(lg[0], lg[1]), fmaxf(lg[2], lg[3]));
    float e0 = __expf(lg[0]-mx), e1 = __expf(lg[1]-mx), e2 = __expf(lg[2]-mx), e3 = __expf(lg[3]-mx);
    float inv = 1.0f / (e0 + e1 + e2 + e3);
    if ((tid & 15) == 0){
      s_gw[r][0] = e0*inv; s_gw[r][1] = e1*inv; s_gw[r][2] = e2*inv; s_gw[r][3] = e3*inv;
    }
  }
  __syncthreads();

  // ---- MoE experts ----
  float mr[4] = {0,0,0,0}, mi[4] = {0,0,0,0};
  for (int e = 0; e < 4; ++e){
    stage64(exp_Wr + e*4096, 64, s_w0, tid);
    stage64(exp_Wi + e*4096, 64, s_w1, tid);
    __syncthreads();
    float er[4], ei[4];
    cproj4(s_zr, s_zi, s_w0, s_w1, g, k, er, ei);
    #pragma unroll
    for (int j = 0; j < 4; ++j){
      float gwv = s_gw[g*4+j][e];
      mr[j] = fmaf(gwv, er[j], mr[j]);
      mi[j] = fmaf(gwv, ei[j], mi[j]);
    }
    __syncthreads();
  }

  { // ---- ComplexLayerNorm (ddof=1) + ModReLU ----
    float lsc = ln_scale[k], lsh = ln_shift[k], mb = mod_bias[k];
    #pragma unroll
    for (int j = 0; j < 4; ++j){
      int r = g*4 + j;
      float h   = sqrtf(mr[j]*mr[j] + mi[j]*mi[j]);
      float mag = h + EPS_F;
      float mean = wave_sum64(mag) * (1.0f/64.0f);
      float diff = mag - mean;
      float var  = wave_sum64(diff*diff) * (1.0f/63.0f);
      float nm   = diff * rsqrtf(var + EPS_F) * lsc + lsh;
      float lr, li;
      if (h > 0.0f){ float ih = 1.0f/h; lr = nm * mr[j] * ih; li = nm * mi[j] * ih; }
      else         { lr = nm; li = 0.0f; }
      float nrm = sqrtf(lr*lr + li*li) + EPS_F;
      float sf  = fmaxf(nrm + mb, 0.0f) / nrm;
      s_ar[r*68 + k] = lr * sf;
      s_ai[r*68 + k] = li * sf;
    }
  }
  __syncthreads();

  // ---- ctx gate: cw = sigmoid(zf @ ctx_W^T + b), 2 phases of 64 cols ----
  for (int ph = 0; ph < 2; ++ph){
    stage64(ctx_W + ph*64*128,      128, s_w0, tid);
    stage64(ctx_W + ph*64*128 + 64, 128, s_w1, tid);
    __syncthreads();
    float cb = ctx_b[ph*64 + k];
    float cc[4] = {cb, cb, cb, cb};
    #pragma unroll 4
    for (int d = 0; d < 64; ++d){
      float a = s_w0[d*65 + k], b = s_w1[d*65 + k];
      #pragma unroll
      for (int j = 0; j < 4; ++j){
        cc[j] = fmaf(s_zr[(g*4+j)*68 + d], a, cc[j]);
        cc[j] = fmaf(s_zi[(g*4+j)*68 + d], b, cc[j]);
      }
    }
    #pragma unroll
    for (int j = 0; j < 4; ++j)
      s_cw[(g*4+j)*132 + ph*64 + k] = 1.0f / (1.0f + __expf(-cc[j]));
    __syncthreads();
  }

  // ---- residual projection: 0.1*(zf @ res_W^T + b) -> ws ----
  for (int ph = 0; ph < 2; ++ph){
    stage64(res_W + ph*64*128,      128, s_w0, tid);
    stage64(res_W + ph*64*128 + 64, 128, s_w1, tid);
    __syncthreads();
    float rb = res_b[ph*64 + k];
    float cc[4] = {rb, rb, rb, rb};
    #pragma unroll 4
    for (int d = 0; d < 64; ++d){
      float a = s_w0[d*65 + k], b = s_w1[d*65 + k];
      #pragma unroll
      for (int j = 0; j < 4; ++j){
        cc[j] = fmaf(s_zr[(g*4+j)*68 + d], a, cc[j]);
        cc[j] = fmaf(s_zi[(g*4+j)*68 + d], b, cc[j]);
      }
    }
    #pragma unroll
    for (int j = 0; j < 4; ++j)
      resb[(size_t)(row0 + g*4 + j)*128 + ph*64 + k] = 0.1f * cc[j];
    __syncthreads();
  }

  { // ---- Q projection (gated) ----
    stage64(q_Wr, 64, s_w0, tid);
    stage64(q_Wi, 64, s_w1, tid);
    __syncthreads();
    float orr[4], oii[4];
    cproj4(s_ar, s_ai, s_w0, s_w1, g, k, orr, oii);
    #pragma unroll
    for (int j = 0; j < 4; ++j){
      int r = g*4 + j; size_t row = row0 + r;
      qf[row*128 + k]      = orr[j] * s_cw[r*132 + k];
      qf[row*128 + 64 + k] = oii[j] * s_cw[r*132 + 64 + k];
    }
    __syncthreads();
  }
  { // ---- K projection ----
    stage64(k_Wr, 64, s_w0, tid);
    stage64(k_Wi, 64, s_w1, tid);
    __syncthreads();
    float orr[4], oii[4];
    cproj4(s_ar, s_ai, s_w0, s_w1, g, k, orr, oii);
    #pragma unroll
    for (int j = 0; j < 4; ++j){
      size_t row = row0 + g*4 + j;
      kf[row*128 + k]      = orr[j];
      kf[row*128 + 64 + k] = oii[j];
    }
    __syncthreads();
  }
  { // ---- V projection ----
    stage64(v_Wr, 64, s_w0, tid);
    stage64(v_Wi, 64, s_w1, tid);
    __syncthreads();
    float orr[4], oii[4];
    cproj4(s_ar, s_ai, s_w0, s_w1, g, k, orr, oii);
    #pragma unroll
    for (int j = 0; j < 4; ++j){
      size_t row = row0 + g*4 + j;
      vf[row*128 + k]      = orr[j];
      vf[row*128 + 64 + k] = oii[j];
    }
  }
}

// ---- chunked flash attention (fp32 SIMT), 4 key chunks of 2048 ----
#define BJ 32

__global__ __launch_bounds__(256, 1) void attn_partial(
    const float* __restrict__ qf, const float* __restrict__ kf, const float* __restrict__ vf,
    float* __restrict__ pacc, float* __restrict__ pm, float* __restrict__ pl)
{
  const int tid  = threadIdx.x;
  const int lane = tid & 63;
  const int w    = tid >> 6;
  const int sub  = lane >> 3;      // 0..7, owns 16 dims
  const int qg   = lane & 7;
  const int qb   = blockIdx.x >> 2;
  const int jc   = blockIdx.x & 3;
  const int q0   = qb*128 + w*32 + qg*4;   // 4 consecutive queries
  const int d0   = sub * 16;

  __shared__ float sk[BJ * 128];
  __shared__ float sv[BJ * 128];

  float4 qreg[4][4];
  #pragma unroll
  for (int c = 0; c < 4; ++c){
    #pragma unroll
    for (int t = 0; t < 4; ++t)
      qreg[c][t] = *reinterpret_cast<const float4*>(qf + (size_t)(q0+c)*128 + d0 + t*4);
  }

  float m[4] = {-3.0e38f, -3.0e38f, -3.0e38f, -3.0e38f};
  float l[4] = {0.f, 0.f, 0.f, 0.f};
  float acc[4][16];
  #pragma unroll
  for (int c = 0; c < 4; ++c){
    #pragma unroll
    for (int t = 0; t < 16; ++t) acc[c][t] = 0.f;
  }

  const int jbase = jc * 2048;
  for (int j0 = 0; j0 < 2048; j0 += BJ){
    const float4* kg = reinterpret_cast<const float4*>(kf + (size_t)(jbase + j0)*128);
    const float4* vg = reinterpret_cast<const float4*>(vf + (size_t)(jbase + j0)*128);
    float4* sk4 = reinterpret_cast<float4*>(sk);
    float4* sv4 = reinterpret_cast<float4*>(sv);
    #pragma unroll
    for (int i = 0; i < 4; ++i){
      int idx = tid + i*256;
      sk4[idx] = kg[idx];
      sv4[idx] = vg[idx];
    }
    __syncthreads();
    for (int jj = 0; jj < BJ; ++jj){
      const float4* kr = reinterpret_cast<const float4*>(sk + jj*128 + d0);
      float4 k0 = kr[0], k1 = kr[1], k2 = kr[2], k3 = kr[3];
      float ps[4];
      #pragma unroll
      for (int c = 0; c < 4; ++c)
        ps[c] = dot4(qreg[c][0],k0) + dot4(qreg[c][1],k1) + dot4(qreg[c][2],k2) + dot4(qreg[c][3],k3);
      #pragma unroll
      for (int c = 0; c < 4; ++c){
        ps[c] += __shfl_xor(ps[c], 8, 64);
        ps[c] += __shfl_xor(ps[c], 16, 64);
        ps[c] += __shfl_xor(ps[c], 32, 64);
      }
      const float4* vr = reinterpret_cast<const float4*>(sv + jj*128 + d0);
      float4 v0 = vr[0], v1 = vr[1], v2 = vr[2], v3 = vr[3];
      #pragma unroll
      for (int c = 0; c < 4; ++c){
        float s = ps[c] * 0.125f;   // ATTN_SCALE = 64^-0.5
        if (s > m[c]){
          float fac = __expf(m[c] - s);
          l[c] *= fac;
          #pragma unroll
          for (int t = 0; t < 16; ++t) acc[c][t] *= fac;
          m[c] = s;
        }
        float pe = __expf(s - m[c]);
        l[c] += pe;
        acc[c][ 0] = fmaf(pe, v0.x, acc[c][ 0]);
        acc[c][ 1] = fmaf(pe, v0.y, acc[c][ 1]);
        acc[c][ 2] = fmaf(pe, v0.z, acc[c][ 2]);
        acc[c][ 3] = fmaf(pe, v0.w, acc[c][ 3]);
        acc[c][ 4] = fmaf(pe, v1.x, acc[c][ 4]);
        acc[c][ 5] = fmaf(pe, v1.y, acc[c][ 5]);
        acc[c][ 6] = fmaf(pe, v1.z, acc[c][ 6]);
        acc[c][ 7] = fmaf(pe, v1.w, acc[c][ 7]);
        acc[c][ 8] = fmaf(pe, v2.x, acc[c][ 8]);
        acc[c][ 9] = fmaf(pe, v2.y, acc[c][ 9]);
        acc[c][10] = fmaf(pe, v2.z, acc[c][10]);
        acc[c][11] = fmaf(pe, v2.w, acc[c][11]);
        acc[c][12] = fmaf(pe, v3.x, acc[c][12]);
        acc[c][13] = fmaf(pe, v3.y, acc[c][13]);
        acc[c][14] = fmaf(pe, v3.z, acc[c][14]);
        acc[c][15] = fmaf(pe, v3.w, acc[c][15]);
      }
    }
    __syncthreads();
  }

  #pragma unroll
  for (int c = 0; c < 4; ++c){
    int q = q0 + c;
    if (sub == 0){ pm[jc*8192 + q] = m[c]; pl[jc*8192 + q] = l[c]; }
    float* dst = pacc + ((size_t)jc*8192 + q)*128 + d0;
    #pragma unroll
    for (int t = 0; t < 16; ++t) dst[t] = acc[c][t];
  }
}

// ---- combine chunk partials + residual + halt/stack heads ----
__global__ __launch_bounds__(256, 1) void combine_kernel(
    const float* __restrict__ pacc, const float* __restrict__ pm, const float* __restrict__ pl,
    const float* __restrict__ resb,
    const float* __restrict__ halt_W, const float* __restrict__ halt_b,
    const float* __restrict__ stack_W, const float* __restrict__ stack_b,
    float* __restrict__ out)
{
  const int tid  = threadIdx.x;
  const int lane = tid & 63;
  const int w    = tid >> 6;
  const int q    = blockIdx.x * 4 + w;

  float mv[4], M = -3.0e38f;
  #pragma unroll
  for (int c = 0; c < 4; ++c){ mv[c] = pm[c*8192 + q]; M = fmaxf(M, mv[c]); }
  float f[4]; float L = 0.f;
  #pragma unroll
  for (int c = 0; c < 4; ++c){ f[c] = __expf(mv[c] - M); L += pl[c*8192 + q] * f[c]; }
  float invL = 1.0f / L;

  float o0 = 0.f, o1 = 0.f;
  #pragma unroll
  for (int c = 0; c < 4; ++c){
    const float* pa = pacc + ((size_t)c*8192 + q)*128;
    o0 += pa[lane]      * f[c];
    o1 += pa[64 + lane] * f[c];
  }
  o0 = o0 * invL + resb[(size_t)q*128 + lane];
  o1 = o1 * invL + resb[(size_t)q*128 + 64 + lane];
  out[(size_t)q*64 + lane] = o0;                       // pr
  out[(size_t)8192*64 + (size_t)q*64 + lane] = o1;     // pi

  float ssq  = wave_sum64(o0*o0 + o1*o1);
  float invn = 1.0f / (sqrtf(ssq) + 1e-6f);
  float zn0 = o0 * invn, zn1 = o1 * invn;
  float hp = wave_sum64(zn0*halt_W[lane]        + zn1*halt_W[64 + lane]);
  float s0 = wave_sum64(zn0*stack_W[lane]       + zn1*stack_W[64 + lane]);
  float s1 = wave_sum64(zn0*stack_W[128 + lane] + zn1*stack_W[192 + lane]);
  float s2 = wave_sum64(zn0*stack_W[256 + lane] + zn1*stack_W[320 + lane]);
  if (lane == 0){
    out[1048576 + q] = hp + halt_b[0];
    out[1056768 + (size_t)q*3 + 0] = s0 + stack_b[0];
    out[1056768 + (size_t)q*3 + 1] = s1 + stack_b[1];
    out[1056768 + (size_t)q*3 + 2] = s2 + stack_b[2];
  }
}

extern "C" void kernel_launch(void* const* d_in, const int* in_sizes, int n_in,
                              void* d_out, int out_size, void* d_ws, size_t ws_size,
                              hipStream_t stream){
  const float* z_real  = (const float*)d_in[0];
  const float* z_imag  = (const float*)d_in[1];
  const float* gate_W  = (const float*)d_in[2];
  const float* gate_b  = (const float*)d_in[3];
  const float* exp_Wr  = (const float*)d_in[4];
  const float* exp_Wi  = (const float*)d_in[5];
  const float* ln_scale= (const float*)d_in[6];
  const float* ln_shift= (const float*)d_in[7];
  const float* mod_bias= (const float*)d_in[8];
  const float* q_Wr    = (const float*)d_in[9];
  const float* q_Wi    = (const float*)d_in[10];
  const float* k_Wr    = (const float*)d_in[11];
  const float* k_Wi    = (const float*)d_in[12];
  const float* v_Wr    = (const float*)d_in[13];
  const float* v_Wi    = (const float*)d_in[14];
  const float* ctx_W   = (const float*)d_in[15];
  const float* ctx_b   = (const float*)d_in[16];
  const float* res_W   = (const float*)d_in[17];
  const float* res_b   = (const float*)d_in[18];
  const float* halt_W  = (const float*)d_in[19];
  const float* halt_b  = (const float*)d_in[20];
  const float* stack_W = (const float*)d_in[21];
  const float* stack_b = (const float*)d_in[22];

  float* ws   = (float*)d_ws;
  float* qf   = ws;
  float* kfb  = qf   + (size_t)8192*128;
  float* vfb  = kfb  + (size_t)8192*128;
  float* resb = vfb  + (size_t)8192*128;
  float* pacc = resb + (size_t)8192*128;
  float* pm   = pacc + (size_t)4*8192*128;
  float* pl   = pm   + 4*8192;

  prep_kernel<<<512, 256, 0, stream>>>(z_real, z_imag, gate_W, gate_b, exp_Wr, exp_Wi,
      ln_scale, ln_shift, mod_bias, q_Wr, q_Wi, k_Wr, k_Wi, v_Wr, v_Wi,
      ctx_W, ctx_b, res_W, res_b, qf, kfb, vfb, resb);
  attn_partial<<<256, 256, 0, stream>>>(qf, kfb, vfb, pacc, pm, pl);
  combine_kernel<<<2048, 256, 0, stream>>>(pacc, pm, pl, resb,
      halt_W, halt_b, stack_W, stack_b, (float*)d_out);
}

// Round 2
// 308.308 us; speedup vs baseline: 3.8281x; 3.8281x over previous
//
#include <hip/hip_runtime.h>
#include <math.h>

#define EPS_F 1e-6f

typedef __attribute__((ext_vector_type(8))) short short8;
typedef __attribute__((ext_vector_type(4))) float f32x4;
typedef unsigned short ushort_t;
typedef unsigned int uint_t;

__device__ __forceinline__ ushort_t f2bf(float x){
  uint_t u = __float_as_uint(x);
  u += 0x7fffu + ((u >> 16) & 1u);
  return (ushort_t)(u >> 16);
}

__device__ __forceinline__ float wave_sum64(float v){
  #pragma unroll
  for (int m = 32; m > 0; m >>= 1) v += __shfl_xor(v, m, 64);
  return v;
}

// Stage a 64x64 block of weights (row-major, given row stride) into LDS
// transposed with pad: s[d*65 + k] = W[k*stride + d].  256 threads.
__device__ __forceinline__ void stage64(const float* __restrict__ W, int row_stride,
                                        float* __restrict__ s, int tid){
  #pragma unroll
  for (int i = 0; i < 4; ++i){
    int g4 = tid + i * 256;
    int kk = g4 >> 4;
    int dd = (g4 & 15) * 4;
    float4 v = *reinterpret_cast<const float4*>(W + kk * row_stride + dd);
    s[(dd + 0) * 65 + kk] = v.x;
    s[(dd + 1) * 65 + kk] = v.y;
    s[(dd + 2) * 65 + kk] = v.z;
    s[(dd + 3) * 65 + kk] = v.w;
  }
}

__device__ __forceinline__ void cproj4(const float* __restrict__ sx, const float* __restrict__ sy,
                                       const float* __restrict__ w0, const float* __restrict__ w1,
                                       int g, int k, float orr[4], float oii[4]){
  #pragma unroll
  for (int j = 0; j < 4; ++j){ orr[j] = 0.f; oii[j] = 0.f; }
  #pragma unroll 4
  for (int d = 0; d < 64; ++d){
    float a = w0[d*65 + k], b = w1[d*65 + k];
    #pragma unroll
    for (int j = 0; j < 4; ++j){
      float xr = sx[(g*4+j)*68 + d];
      float xi = sy[(g*4+j)*68 + d];
      orr[j] = fmaf(xr, a, orr[j]);
      orr[j] = fmaf(-xi, b, orr[j]);
      oii[j] = fmaf(xi, a, oii[j]);
      oii[j] = fmaf(xr, b, oii[j]);
    }
  }
}

#define RA 16

__global__ __launch_bounds__(256, 1) void prep_kernel(
    const float* __restrict__ z_real, const float* __restrict__ z_imag,
    const float* __restrict__ gate_W, const float* __restrict__ gate_b,
    const float* __restrict__ exp_Wr, const float* __restrict__ exp_Wi,
    const float* __restrict__ ln_scale, const float* __restrict__ ln_shift,
    const float* __restrict__ mod_bias,
    const float* __restrict__ q_Wr, const float* __restrict__ q_Wi,
    const float* __restrict__ k_Wr, const float* __restrict__ k_Wi,
    const float* __restrict__ v_Wr, const float* __restrict__ v_Wi,
    const float* __restrict__ ctx_W, const float* __restrict__ ctx_b,
    const float* __restrict__ res_W, const float* __restrict__ res_b,
    ushort_t* __restrict__ qf, ushort_t* __restrict__ kf, ushort_t* __restrict__ vf,
    float* __restrict__ resb)
{
  const int tid = threadIdx.x;
  const int k   = tid & 63;
  const int g   = tid >> 6;
  const int row0 = blockIdx.x * RA;

  __shared__ float s_zr[RA * 68];
  __shared__ float s_zi[RA * 68];
  __shared__ float s_ar[RA * 68];
  __shared__ float s_ai[RA * 68];
  __shared__ float s_cw[RA * 132];
  __shared__ float s_gw[RA][4];
  __shared__ float s_w0[64 * 65];
  __shared__ float s_w1[64 * 65];

  {
    int r  = tid >> 4;
    int dd = (tid & 15) * 4;
    float4 a = *reinterpret_cast<const float4*>(z_real + (size_t)(row0 + r) * 64 + dd);
    float4 b = *reinterpret_cast<const float4*>(z_imag + (size_t)(row0 + r) * 64 + dd);
    *reinterpret_cast<float4*>(s_zr + r * 68 + dd) = a;
    *reinterpret_cast<float4*>(s_zi + r * 68 + dd) = b;
  }
  __syncthreads();

  {
    int r = tid >> 4;
    float lg[4];
    #pragma unroll
    for (int e = 0; e < 4; ++e){
      float acc = gate_b[e];
      #pragma unroll 8
      for (int d = 0; d < 64; ++d)
        acc += s_zr[r*68 + d] * gate_W[e*128 + d] + s_zi[r*68 + d] * gate_W[e*128 + 64 + d];
      lg[e] = acc;
    }
    float mx = fmaxf(fmaxf(lg[0], lg[1]), fmaxf(lg[2], lg[3]));
    float e0 = __expf(lg[0]-mx), e1 = __expf(lg[1]-mx), e2 = __expf(lg[2]-mx), e3 = __expf(lg[3]-mx);
    float inv = 1.0f / (e0 + e1 + e2 + e3);
    if ((tid & 15) == 0){
      s_gw[r][0] = e0*inv; s_gw[r][1] = e1*inv; s_gw[r][2] = e2*inv; s_gw[r][3] = e3*inv;
    }
  }
  __syncthreads();

  // ---- MoE experts ----
  float mr[4] = {0,0,0,0}, mi[4] = {0,0,0,0};
  for (int e = 0; e < 4; ++e){
    stage64(exp_Wr + e*4096, 64, s_w0, tid);
    stage64(exp_Wi + e*4096, 64, s_w1, tid);
    __syncthreads();
    float er[4], ei[4];
    cproj4(s_zr, s_zi, s_w0, s_w1, g, k, er, ei);
    #pragma unroll
    for (int j = 0; j < 4; ++j){
      float gwv = s_gw[g*4+j][e];
      mr[j] = fmaf(gwv, er[j], mr[j]);
      mi[j] = fmaf(gwv, ei[j], mi[j]);
    }
    __syncthreads();
  }

  { // ---- ComplexLayerNorm (ddof=1) + ModReLU ----
    float lsc = ln_scale[k], lsh = ln_shift[k], mb = mod_bias[k];
    #pragma unroll
    for (int j = 0; j < 4; ++j){
      int r = g*4 + j;
      float h   = sqrtf(mr[j]*mr[j] + mi[j]*mi[j]);
      float mag = h + EPS_F;
      float mean = wave_sum64(mag) * (1.0f/64.0f);
      float diff = mag - mean;
      float var  = wave_sum64(diff*diff) * (1.0f/63.0f);
      float nm   = diff * rsqrtf(var + EPS_F) * lsc + lsh;
      float lr, li;
      if (h > 0.0f){ float ih = 1.0f/h; lr = nm * mr[j] * ih; li = nm * mi[j] * ih; }
      else         { lr = nm; li = 0.0f; }
      float nrm = sqrtf(lr*lr + li*li) + EPS_F;
      float sf  = fmaxf(nrm + mb, 0.0f) / nrm;
      s_ar[r*68 + k] = lr * sf;
      s_ai[r*68 + k] = li * sf;
    }
  }
  __syncthreads();

  // ---- ctx gate ----
  for (int ph = 0; ph < 2; ++ph){
    stage64(ctx_W + ph*64*128,      128, s_w0, tid);
    stage64(ctx_W + ph*64*128 + 64, 128, s_w1, tid);
    __syncthreads();
    float cb = ctx_b[ph*64 + k];
    float cc[4] = {cb, cb, cb, cb};
    #pragma unroll 4
    for (int d = 0; d < 64; ++d){
      float a = s_w0[d*65 + k], b = s_w1[d*65 + k];
      #pragma unroll
      for (int j = 0; j < 4; ++j){
        cc[j] = fmaf(s_zr[(g*4+j)*68 + d], a, cc[j]);
        cc[j] = fmaf(s_zi[(g*4+j)*68 + d], b, cc[j]);
      }
    }
    #pragma unroll
    for (int j = 0; j < 4; ++j)
      s_cw[(g*4+j)*132 + ph*64 + k] = 1.0f / (1.0f + __expf(-cc[j]));
    __syncthreads();
  }

  // ---- residual projection ----
  for (int ph = 0; ph < 2; ++ph){
    stage64(res_W + ph*64*128,      128, s_w0, tid);
    stage64(res_W + ph*64*128 + 64, 128, s_w1, tid);
    __syncthreads();
    float rb = res_b[ph*64 + k];
    float cc[4] = {rb, rb, rb, rb};
    #pragma unroll 4
    for (int d = 0; d < 64; ++d){
      float a = s_w0[d*65 + k], b = s_w1[d*65 + k];
      #pragma unroll
      for (int j = 0; j < 4; ++j){
        cc[j] = fmaf(s_zr[(g*4+j)*68 + d], a, cc[j]);
        cc[j] = fmaf(s_zi[(g*4+j)*68 + d], b, cc[j]);
      }
    }
    #pragma unroll
    for (int j = 0; j < 4; ++j)
      resb[(size_t)(row0 + g*4 + j)*128 + ph*64 + k] = 0.1f * cc[j];
    __syncthreads();
  }

  { // ---- Q projection (gated, ATTN_SCALE folded, bf16 out) ----
    stage64(q_Wr, 64, s_w0, tid);
    stage64(q_Wi, 64, s_w1, tid);
    __syncthreads();
    float orr[4], oii[4];
    cproj4(s_ar, s_ai, s_w0, s_w1, g, k, orr, oii);
    #pragma unroll
    for (int j = 0; j < 4; ++j){
      int r = g*4 + j; size_t row = row0 + r;
      qf[row*128 + k]      = f2bf(orr[j] * s_cw[r*132 + k]      * 0.125f);
      qf[row*128 + 64 + k] = f2bf(oii[j] * s_cw[r*132 + 64 + k] * 0.125f);
    }
    __syncthreads();
  }
  { // ---- K projection (bf16 out) ----
    stage64(k_Wr, 64, s_w0, tid);
    stage64(k_Wi, 64, s_w1, tid);
    __syncthreads();
    float orr[4], oii[4];
    cproj4(s_ar, s_ai, s_w0, s_w1, g, k, orr, oii);
    #pragma unroll
    for (int j = 0; j < 4; ++j){
      size_t row = row0 + g*4 + j;
      kf[row*128 + k]      = f2bf(orr[j]);
      kf[row*128 + 64 + k] = f2bf(oii[j]);
    }
    __syncthreads();
  }
  { // ---- V projection (bf16 out) ----
    stage64(v_Wr, 64, s_w0, tid);
    stage64(v_Wi, 64, s_w1, tid);
    __syncthreads();
    float orr[4], oii[4];
    cproj4(s_ar, s_ai, s_w0, s_w1, g, k, orr, oii);
    #pragma unroll
    for (int j = 0; j < 4; ++j){
      size_t row = row0 + g*4 + j;
      vf[row*128 + k]      = f2bf(orr[j]);
      vf[row*128 + 64 + k] = f2bf(oii[j]);
    }
  }
}

// ---- MFMA flash attention: 128 q-blocks x 4 key-chunks ----
// Block: 4 waves, each wave owns 16 query rows. KV tile = 32 rows.
__global__ __launch_bounds__(256, 2) void attn_mfma(
    const ushort_t* __restrict__ qf, const ushort_t* __restrict__ kf, const ushort_t* __restrict__ vf,
    float* __restrict__ pacc, float* __restrict__ pm, float* __restrict__ pl)
{
  const int tid  = threadIdx.x;
  const int lane = tid & 63;
  const int w    = tid >> 6;
  const int g    = lane >> 4;      // 0..3
  const int hl   = lane & 15;      // 0..15
  const int qb   = blockIdx.x >> 2;
  const int jc   = blockIdx.x & 3;
  const int q0   = qb * 64;
  const int qr   = q0 + w*16 + hl; // A-frag row (row = lane&15)

  __shared__ ushort_t s_k[32][136];    // K tile row-major
  __shared__ ushort_t s_vt[128][40];   // V tile transposed: s_vt[d][j]
  __shared__ ushort_t s_p[4][16][40];  // per-wave P tile

  // Q fragments: lane holds Q[qr][kt*32 + g*8 + e], e=0..7
  short8 qfrag[4];
  #pragma unroll
  for (int kt = 0; kt < 4; ++kt)
    qfrag[kt] = *reinterpret_cast<const short8*>(qf + (size_t)qr*128 + kt*32 + g*8);

  f32x4 oacc[8];
  #pragma unroll
  for (int dt = 0; dt < 8; ++dt) oacc[dt] = (f32x4){0.f, 0.f, 0.f, 0.f};
  float mrun[4], lrun[4];
  #pragma unroll
  for (int r = 0; r < 4; ++r){ mrun[r] = -3.0e38f; lrun[r] = 0.f; }

  const int jend = jc*2048 + 2048;
  for (int j0 = jc*2048; j0 < jend; j0 += 32){
    __syncthreads();
    // ---- stage K (row-major) and V (transposed) ----
    #pragma unroll
    for (int i = 0; i < 2; ++i){
      int idx = tid + i*256;           // 0..511 groups of 8 elems
      int jj  = idx >> 4;
      int kk  = (idx & 15) * 8;
      uint4 kv = *reinterpret_cast<const uint4*>(kf + (size_t)(j0+jj)*128 + kk);
      *reinterpret_cast<uint4*>(&s_k[jj][kk]) = kv;
      uint4 vv = *reinterpret_cast<const uint4*>(vf + (size_t)(j0+jj)*128 + kk);
      const ushort_t* pv = reinterpret_cast<const ushort_t*>(&vv);
      #pragma unroll
      for (int e = 0; e < 8; ++e) s_vt[kk+e][jj] = pv[e];
    }
    __syncthreads();

    // ---- QK^T: S[16q][32j], 2 n-tiles x 4 k-steps ----
    f32x4 sacc[2];
    #pragma unroll
    for (int jt = 0; jt < 2; ++jt){
      sacc[jt] = (f32x4){0.f, 0.f, 0.f, 0.f};
      #pragma unroll
      for (int kt = 0; kt < 4; ++kt){
        short8 kfr = *reinterpret_cast<const short8*>(&s_k[jt*16 + hl][kt*32 + g*8]);
        sacc[jt] = __builtin_amdgcn_mfma_f32_16x16x32_bf16(qfrag[kt], kfr, sacc[jt], 0, 0, 0);
      }
    }

    // ---- online softmax. C layout: lane(g,hl) reg r -> S[4g+r][jt*16+hl] ----
    float pe[2][4];
    #pragma unroll
    for (int r = 0; r < 4; ++r){
      float t = fmaxf(sacc[0][r], sacc[1][r]);
      #pragma unroll
      for (int msk = 1; msk < 16; msk <<= 1) t = fmaxf(t, __shfl_xor(t, msk, 64));
      float mnew = fmaxf(mrun[r], t);
      float fac  = __expf(mrun[r] - mnew);
      mrun[r] = mnew;
      float p0 = __expf(sacc[0][r] - mnew);
      float p1 = __expf(sacc[1][r] - mnew);
      pe[0][r] = p0; pe[1][r] = p1;
      float ts = p0 + p1;
      #pragma unroll
      for (int msk = 1; msk < 16; msk <<= 1) ts += __shfl_xor(ts, msk, 64);
      lrun[r] = lrun[r] * fac + ts;
      #pragma unroll
      for (int dt = 0; dt < 8; ++dt) oacc[dt][r] *= fac;
    }

    // ---- P -> per-wave LDS (bf16), re-layout to A-fragment ----
    #pragma unroll
    for (int jt = 0; jt < 2; ++jt)
      #pragma unroll
      for (int r = 0; r < 4; ++r)
        s_p[w][4*g + r][jt*16 + hl] = f2bf(pe[jt][r]);

    short8 pfrag = *reinterpret_cast<const short8*>(&s_p[w][hl][g*8]);

    // ---- PV: O[16q][128d] += P[16q][32j] @ V[32j][128d] ----
    #pragma unroll
    for (int dt = 0; dt < 8; ++dt){
      short8 vfr = *reinterpret_cast<const short8*>(&s_vt[dt*16 + hl][g*8]);
      oacc[dt] = __builtin_amdgcn_mfma_f32_16x16x32_bf16(pfrag, vfr, oacc[dt], 0, 0, 0);
    }
  }

  // ---- write partials ----
  #pragma unroll
  for (int dt = 0; dt < 8; ++dt)
    #pragma unroll
    for (int r = 0; r < 4; ++r)
      pacc[((size_t)jc*8192 + q0 + w*16 + 4*g + r)*128 + dt*16 + hl] = oacc[dt][r];

  if (hl < 4){
    float mv = (hl==0) ? mrun[0] : (hl==1) ? mrun[1] : (hl==2) ? mrun[2] : mrun[3];
    float lv = (hl==0) ? lrun[0] : (hl==1) ? lrun[1] : (hl==2) ? lrun[2] : lrun[3];
    int q = q0 + w*16 + 4*g + hl;
    pm[jc*8192 + q] = mv;
    pl[jc*8192 + q] = lv;
  }
}

// ---- combine chunk partials + residual + halt/stack heads ----
__global__ __launch_bounds__(256, 1) void combine_kernel(
    const float* __restrict__ pacc, const float* __restrict__ pm, const float* __restrict__ pl,
    const float* __restrict__ resb,
    const float* __restrict__ halt_W, const float* __restrict__ halt_b,
    const float* __restrict__ stack_W, const float* __restrict__ stack_b,
    float* __restrict__ out)
{
  const int tid  = threadIdx.x;
  const int lane = tid & 63;
  const int w    = tid >> 6;
  const int q    = blockIdx.x * 4 + w;

  float mv[4], M = -3.0e38f;
  #pragma unroll
  for (int c = 0; c < 4; ++c){ mv[c] = pm[c*8192 + q]; M = fmaxf(M, mv[c]); }
  float f[4]; float L = 0.f;
  #pragma unroll
  for (int c = 0; c < 4; ++c){ f[c] = __expf(mv[c] - M); L += pl[c*8192 + q] * f[c]; }
  float invL = 1.0f / L;

  float o0 = 0.f, o1 = 0.f;
  #pragma unroll
  for (int c = 0; c < 4; ++c){
    const float* pa = pacc + ((size_t)c*8192 + q)*128;
    o0 += pa[lane]      * f[c];
    o1 += pa[64 + lane] * f[c];
  }
  o0 = o0 * invL + resb[(size_t)q*128 + lane];
  o1 = o1 * invL + resb[(size_t)q*128 + 64 + lane];
  out[(size_t)q*64 + lane] = o0;
  out[(size_t)8192*64 + (size_t)q*64 + lane] = o1;

  float ssq  = wave_sum64(o0*o0 + o1*o1);
  float invn = 1.0f / (sqrtf(ssq) + 1e-6f);
  float zn0 = o0 * invn, zn1 = o1 * invn;
  float hp = wave_sum64(zn0*halt_W[lane]        + zn1*halt_W[64 + lane]);
  float s0 = wave_sum64(zn0*stack_W[lane]       + zn1*stack_W[64 + lane]);
  float s1 = wave_sum64(zn0*stack_W[128 + lane] + zn1*stack_W[192 + lane]);
  float s2 = wave_sum64(zn0*stack_W[256 + lane] + zn1*stack_W[320 + lane]);
  if (lane == 0){
    out[1048576 + q] = hp + halt_b[0];
    out[1056768 + (size_t)q*3 + 0] = s0 + stack_b[0];
    out[1056768 + (size_t)q*3 + 1] = s1 + stack_b[1];
    out[1056768 + (size_t)q*3 + 2] = s2 + stack_b[2];
  }
}

extern "C" void kernel_launch(void* const* d_in, const int* in_sizes, int n_in,
                              void* d_out, int out_size, void* d_ws, size_t ws_size,
                              hipStream_t stream){
  const float* z_real  = (const float*)d_in[0];
  const float* z_imag  = (const float*)d_in[1];
  const float* gate_W  = (const float*)d_in[2];
  const float* gate_b  = (const float*)d_in[3];
  const float* exp_Wr  = (const float*)d_in[4];
  const float* exp_Wi  = (const float*)d_in[5];
  const float* ln_scale= (const float*)d_in[6];
  const float* ln_shift= (const float*)d_in[7];
  const float* mod_bias= (const float*)d_in[8];
  const float* q_Wr    = (const float*)d_in[9];
  const float* q_Wi    = (const float*)d_in[10];
  const float* k_Wr    = (const float*)d_in[11];
  const float* k_Wi    = (const float*)d_in[12];
  const float* v_Wr    = (const float*)d_in[13];
  const float* v_Wi    = (const float*)d_in[14];
  const float* ctx_W   = (const float*)d_in[15];
  const float* ctx_b   = (const float*)d_in[16];
  const float* res_W   = (const float*)d_in[17];
  const float* res_b   = (const float*)d_in[18];
  const float* halt_W  = (const float*)d_in[19];
  const float* halt_b  = (const float*)d_in[20];
  const float* stack_W = (const float*)d_in[21];
  const float* stack_b = (const float*)d_in[22];

  ushort_t* qbf = (ushort_t*)d_ws;
  ushort_t* kbf = qbf + (size_t)8192*128;
  ushort_t* vbf = kbf + (size_t)8192*128;
  float* resb = (float*)(vbf + (size_t)8192*128);
  float* pacc = resb + (size_t)8192*128;
  float* pm   = pacc + (size_t)4*8192*128;
  float* pl   = pm   + 4*8192;

  prep_kernel<<<512, 256, 0, stream>>>(z_real, z_imag, gate_W, gate_b, exp_Wr, exp_Wi,
      ln_scale, ln_shift, mod_bias, q_Wr, q_Wi, k_Wr, k_Wi, v_Wr, v_Wi,
      ctx_W, ctx_b, res_W, res_b, qbf, kbf, vbf, resb);
  attn_mfma<<<512, 256, 0, stream>>>(qbf, kbf, vbf, pacc, pm, pl);
  combine_kernel<<<2048, 256, 0, stream>>>(pacc, pm, pl, resb,
      halt_W, halt_b, stack_W, stack_b, (float*)d_out);
}

// Round 3
// 227.917 us; speedup vs baseline: 5.1783x; 1.3527x over previous
//
#include <hip/hip_runtime.h>
#include <math.h>

#define EPS_F 1e-6f
#define NCH   8          // KV chunks
#define CHUNK 1024       // 8192 / NCH
#define TILES 32         // CHUNK / 32

typedef __attribute__((ext_vector_type(8))) short short8;
typedef __attribute__((ext_vector_type(4))) float f32x4;
typedef unsigned short ushort_t;
typedef unsigned int uint_t;

__device__ __forceinline__ ushort_t f2bf(float x){
  uint_t u = __float_as_uint(x);
  u += 0x7fffu + ((u >> 16) & 1u);
  return (ushort_t)(u >> 16);
}
__device__ __forceinline__ float bf2f(ushort_t u){
  return __uint_as_float(((uint_t)u) << 16);
}

__device__ __forceinline__ float wave_sum64(float v){
  #pragma unroll
  for (int m = 32; m > 0; m >>= 1) v += __shfl_xor(v, m, 64);
  return v;
}

// Stage a 64x64 block of weights (row-major, given row stride) into LDS
// transposed with pad: s[d*65 + k] = W[k*stride + d].  256 threads.
__device__ __forceinline__ void stage64(const float* __restrict__ W, int row_stride,
                                        float* __restrict__ s, int tid){
  #pragma unroll
  for (int i = 0; i < 4; ++i){
    int g4 = tid + i * 256;
    int kk = g4 >> 4;
    int dd = (g4 & 15) * 4;
    float4 v = *reinterpret_cast<const float4*>(W + kk * row_stride + dd);
    s[(dd + 0) * 65 + kk] = v.x;
    s[(dd + 1) * 65 + kk] = v.y;
    s[(dd + 2) * 65 + kk] = v.z;
    s[(dd + 3) * 65 + kk] = v.w;
  }
}

__device__ __forceinline__ void cproj4(const float* __restrict__ sx, const float* __restrict__ sy,
                                       const float* __restrict__ w0, const float* __restrict__ w1,
                                       int g, int k, float orr[4], float oii[4]){
  #pragma unroll
  for (int j = 0; j < 4; ++j){ orr[j] = 0.f; oii[j] = 0.f; }
  #pragma unroll 4
  for (int d = 0; d < 64; ++d){
    float a = w0[d*65 + k], b = w1[d*65 + k];
    #pragma unroll
    for (int j = 0; j < 4; ++j){
      float xr = sx[(g*4+j)*68 + d];
      float xi = sy[(g*4+j)*68 + d];
      orr[j] = fmaf(xr, a, orr[j]);
      orr[j] = fmaf(-xi, b, orr[j]);
      oii[j] = fmaf(xi, a, oii[j]);
      oii[j] = fmaf(xr, b, oii[j]);
    }
  }
}

#define RA 16

__global__ __launch_bounds__(256, 1) void prep_kernel(
    const float* __restrict__ z_real, const float* __restrict__ z_imag,
    const float* __restrict__ gate_W, const float* __restrict__ gate_b,
    const float* __restrict__ exp_Wr, const float* __restrict__ exp_Wi,
    const float* __restrict__ ln_scale, const float* __restrict__ ln_shift,
    const float* __restrict__ mod_bias,
    const float* __restrict__ q_Wr, const float* __restrict__ q_Wi,
    const float* __restrict__ k_Wr, const float* __restrict__ k_Wi,
    const float* __restrict__ v_Wr, const float* __restrict__ v_Wi,
    const float* __restrict__ ctx_W, const float* __restrict__ ctx_b,
    const float* __restrict__ res_W, const float* __restrict__ res_b,
    ushort_t* __restrict__ qf, ushort_t* __restrict__ kf, ushort_t* __restrict__ vt,
    float* __restrict__ resb)
{
  const int tid = threadIdx.x;
  const int k   = tid & 63;
  const int g   = tid >> 6;
  const int row0 = blockIdx.x * RA;

  __shared__ float s_zr[RA * 68];
  __shared__ float s_zi[RA * 68];
  __shared__ float s_ar[RA * 68];
  __shared__ float s_ai[RA * 68];
  __shared__ float s_cw[RA * 132];
  __shared__ float s_gw[RA][4];
  __shared__ float s_w0[64 * 65];
  __shared__ float s_w1[64 * 65];
  __shared__ ushort_t s_tv[128][20];   // V^T staging: s_tv[d][local_row]

  {
    int r  = tid >> 4;
    int dd = (tid & 15) * 4;
    float4 a = *reinterpret_cast<const float4*>(z_real + (size_t)(row0 + r) * 64 + dd);
    float4 b = *reinterpret_cast<const float4*>(z_imag + (size_t)(row0 + r) * 64 + dd);
    *reinterpret_cast<float4*>(s_zr + r * 68 + dd) = a;
    *reinterpret_cast<float4*>(s_zi + r * 68 + dd) = b;
  }
  __syncthreads();

  {
    int r = tid >> 4;
    float lg[4];
    #pragma unroll
    for (int e = 0; e < 4; ++e){
      float acc = gate_b[e];
      #pragma unroll 8
      for (int d = 0; d < 64; ++d)
        acc += s_zr[r*68 + d] * gate_W[e*128 + d] + s_zi[r*68 + d] * gate_W[e*128 + 64 + d];
      lg[e] = acc;
    }
    float mx = fmaxf(fmaxf(lg[0], lg[1]), fmaxf(lg[2], lg[3]));
    float e0 = __expf(lg[0]-mx), e1 = __expf(lg[1]-mx), e2 = __expf(lg[2]-mx), e3 = __expf(lg[3]-mx);
    float inv = 1.0f / (e0 + e1 + e2 + e3);
    if ((tid & 15) == 0){
      s_gw[r][0] = e0*inv; s_gw[r][1] = e1*inv; s_gw[r][2] = e2*inv; s_gw[r][3] = e3*inv;
    }
  }
  __syncthreads();

  // ---- MoE experts ----
  float mr[4] = {0,0,0,0}, mi[4] = {0,0,0,0};
  for (int e = 0; e < 4; ++e){
    stage64(exp_Wr + e*4096, 64, s_w0, tid);
    stage64(exp_Wi + e*4096, 64, s_w1, tid);
    __syncthreads();
    float er[4], ei[4];
    cproj4(s_zr, s_zi, s_w0, s_w1, g, k, er, ei);
    #pragma unroll
    for (int j = 0; j < 4; ++j){
      float gwv = s_gw[g*4+j][e];
      mr[j] = fmaf(gwv, er[j], mr[j]);
      mi[j] = fmaf(gwv, ei[j], mi[j]);
    }
    __syncthreads();
  }

  { // ---- ComplexLayerNorm (ddof=1) + ModReLU ----
    float lsc = ln_scale[k], lsh = ln_shift[k], mb = mod_bias[k];
    #pragma unroll
    for (int j = 0; j < 4; ++j){
      int r = g*4 + j;
      float h   = sqrtf(mr[j]*mr[j] + mi[j]*mi[j]);
      float mag = h + EPS_F;
      float mean = wave_sum64(mag) * (1.0f/64.0f);
      float diff = mag - mean;
      float var  = wave_sum64(diff*diff) * (1.0f/63.0f);
      float nm   = diff * rsqrtf(var + EPS_F) * lsc + lsh;
      float lr, li;
      if (h > 0.0f){ float ih = 1.0f/h; lr = nm * mr[j] * ih; li = nm * mi[j] * ih; }
      else         { lr = nm; li = 0.0f; }
      float nrm = sqrtf(lr*lr + li*li) + EPS_F;
      float sf  = fmaxf(nrm + mb, 0.0f) / nrm;
      s_ar[r*68 + k] = lr * sf;
      s_ai[r*68 + k] = li * sf;
    }
  }
  __syncthreads();

  // ---- ctx gate ----
  for (int ph = 0; ph < 2; ++ph){
    stage64(ctx_W + ph*64*128,      128, s_w0, tid);
    stage64(ctx_W + ph*64*128 + 64, 128, s_w1, tid);
    __syncthreads();
    float cb = ctx_b[ph*64 + k];
    float cc[4] = {cb, cb, cb, cb};
    #pragma unroll 4
    for (int d = 0; d < 64; ++d){
      float a = s_w0[d*65 + k], b = s_w1[d*65 + k];
      #pragma unroll
      for (int j = 0; j < 4; ++j){
        cc[j] = fmaf(s_zr[(g*4+j)*68 + d], a, cc[j]);
        cc[j] = fmaf(s_zi[(g*4+j)*68 + d], b, cc[j]);
      }
    }
    #pragma unroll
    for (int j = 0; j < 4; ++j)
      s_cw[(g*4+j)*132 + ph*64 + k] = 1.0f / (1.0f + __expf(-cc[j]));
    __syncthreads();
  }

  // ---- residual projection ----
  for (int ph = 0; ph < 2; ++ph){
    stage64(res_W + ph*64*128,      128, s_w0, tid);
    stage64(res_W + ph*64*128 + 64, 128, s_w1, tid);
    __syncthreads();
    float rb = res_b[ph*64 + k];
    float cc[4] = {rb, rb, rb, rb};
    #pragma unroll 4
    for (int d = 0; d < 64; ++d){
      float a = s_w0[d*65 + k], b = s_w1[d*65 + k];
      #pragma unroll
      for (int j = 0; j < 4; ++j){
        cc[j] = fmaf(s_zr[(g*4+j)*68 + d], a, cc[j]);
        cc[j] = fmaf(s_zi[(g*4+j)*68 + d], b, cc[j]);
      }
    }
    #pragma unroll
    for (int j = 0; j < 4; ++j)
      resb[(size_t)(row0 + g*4 + j)*128 + ph*64 + k] = 0.1f * cc[j];
    __syncthreads();
  }

  { // ---- Q projection (gated, ATTN_SCALE folded, bf16 out) ----
    stage64(q_Wr, 64, s_w0, tid);
    stage64(q_Wi, 64, s_w1, tid);
    __syncthreads();
    float orr[4], oii[4];
    cproj4(s_ar, s_ai, s_w0, s_w1, g, k, orr, oii);
    #pragma unroll
    for (int j = 0; j < 4; ++j){
      int r = g*4 + j; size_t row = row0 + r;
      qf[row*128 + k]      = f2bf(orr[j] * s_cw[r*132 + k]      * 0.125f);
      qf[row*128 + 64 + k] = f2bf(oii[j] * s_cw[r*132 + 64 + k] * 0.125f);
    }
    __syncthreads();
  }
  { // ---- K projection (bf16 out) ----
    stage64(k_Wr, 64, s_w0, tid);
    stage64(k_Wi, 64, s_w1, tid);
    __syncthreads();
    float orr[4], oii[4];
    cproj4(s_ar, s_ai, s_w0, s_w1, g, k, orr, oii);
    #pragma unroll
    for (int j = 0; j < 4; ++j){
      size_t row = row0 + g*4 + j;
      kf[row*128 + k]      = f2bf(orr[j]);
      kf[row*128 + 64 + k] = f2bf(oii[j]);
    }
    __syncthreads();
  }
  { // ---- V projection (bf16, TRANSPOSED to global vt[128][8192]) ----
    stage64(v_Wr, 64, s_w0, tid);
    stage64(v_Wi, 64, s_w1, tid);
    __syncthreads();
    float orr[4], oii[4];
    cproj4(s_ar, s_ai, s_w0, s_w1, g, k, orr, oii);
    #pragma unroll
    for (int j = 0; j < 4; ++j){
      s_tv[k]     [g*4 + j] = f2bf(orr[j]);
      s_tv[64 + k][g*4 + j] = f2bf(oii[j]);
    }
    __syncthreads();
    // write out: thread -> (d = tid>>1, half = tid&1), 16 bytes each
    int d = tid >> 1, half = tid & 1;
    uint2 a = *reinterpret_cast<const uint2*>(&s_tv[d][half*8]);
    uint2 b = *reinterpret_cast<const uint2*>(&s_tv[d][half*8 + 4]);
    uint4 o; o.x = a.x; o.y = a.y; o.z = b.x; o.w = b.y;
    *reinterpret_cast<uint4*>(vt + (size_t)d*8192 + row0 + half*8) = o;
  }
}

// ---- MFMA flash attention: 128 q-blocks x NCH key-chunks ----
// Block: 4 waves, each wave owns 16 query rows. KV tile = 32 rows.
// V is pre-transposed in global (vt[128][8192]) -> vectorized staging.
__global__ __launch_bounds__(256, 2) void attn_mfma(
    const ushort_t* __restrict__ qf, const ushort_t* __restrict__ kf, const ushort_t* __restrict__ vt,
    ushort_t* __restrict__ pacc, float* __restrict__ pm, float* __restrict__ pl)
{
  const int tid  = threadIdx.x;
  const int lane = tid & 63;
  const int w    = tid >> 6;
  const int g    = lane >> 4;      // 0..3
  const int hl   = lane & 15;      // 0..15
  const int qb   = blockIdx.x & 127;
  const int jc   = blockIdx.x >> 7;
  const int q0   = qb * 64;
  const int qr   = q0 + w*16 + hl;

  __shared__ ushort_t s_k[32][136];    // K tile row-major (pad 136)
  __shared__ ushort_t s_vt[128][40];   // V^T tile: s_vt[d][j] (pad 40)
  __shared__ ushort_t s_p[4][16][40];  // per-wave P tile

  // staging address precompute
  const int kjj0 = tid >> 4;            // K: row within tile (i*16 offset)
  const int kkk  = (tid & 15) * 8;      // K: col
  const int vd0  = tid >> 2;            // V: d row (i*64 offset)
  const int vjo  = (tid & 3) * 8;       // V: j within tile

  // Q fragments: lane holds Q[qr][kt*32 + g*8 + e], e=0..7
  short8 qfrag[4];
  #pragma unroll
  for (int kt = 0; kt < 4; ++kt)
    qfrag[kt] = *reinterpret_cast<const short8*>(qf + (size_t)qr*128 + kt*32 + g*8);

  f32x4 oacc[8];
  #pragma unroll
  for (int dt = 0; dt < 8; ++dt) oacc[dt] = (f32x4){0.f, 0.f, 0.f, 0.f};
  float mrun[4], lrun[4];
  #pragma unroll
  for (int r = 0; r < 4; ++r){ mrun[r] = -3.0e38f; lrun[r] = 0.f; }

  const int jstart = jc * CHUNK;

  uint4 kreg[2], vreg[2];
  // preload tile 0
  #pragma unroll
  for (int i = 0; i < 2; ++i){
    kreg[i] = *reinterpret_cast<const uint4*>(kf + (size_t)(jstart + kjj0 + i*16)*128 + kkk);
    vreg[i] = *reinterpret_cast<const uint4*>(vt + (size_t)(vd0 + i*64)*8192 + jstart + vjo);
  }

  for (int t = 0; t < TILES; ++t){
    __syncthreads();   // previous tile's compute done
    #pragma unroll
    for (int i = 0; i < 2; ++i){
      *reinterpret_cast<uint4*>(&s_k[kjj0 + i*16][kkk]) = kreg[i];
      *reinterpret_cast<uint4*>(&s_vt[vd0 + i*64][vjo]) = vreg[i];
    }
    __syncthreads();
    if (t + 1 < TILES){
      const int jn = jstart + (t+1)*32;
      #pragma unroll
      for (int i = 0; i < 2; ++i){
        kreg[i] = *reinterpret_cast<const uint4*>(kf + (size_t)(jn + kjj0 + i*16)*128 + kkk);
        vreg[i] = *reinterpret_cast<const uint4*>(vt + (size_t)(vd0 + i*64)*8192 + jn + vjo);
      }
    }

    // ---- QK^T: S[16q][32j] ----
    f32x4 sacc[2];
    #pragma unroll
    for (int jt = 0; jt < 2; ++jt){
      sacc[jt] = (f32x4){0.f, 0.f, 0.f, 0.f};
      #pragma unroll
      for (int kt = 0; kt < 4; ++kt){
        short8 kfr = *reinterpret_cast<const short8*>(&s_k[jt*16 + hl][kt*32 + g*8]);
        sacc[jt] = __builtin_amdgcn_mfma_f32_16x16x32_bf16(qfrag[kt], kfr, sacc[jt], 0, 0, 0);
      }
    }

    // ---- online softmax. C layout: lane(g,hl) reg r -> S[4g+r][jt*16+hl] ----
    float pe[2][4];
    #pragma unroll
    for (int r = 0; r < 4; ++r){
      float tmx = fmaxf(sacc[0][r], sacc[1][r]);
      #pragma unroll
      for (int msk = 1; msk < 16; msk <<= 1) tmx = fmaxf(tmx, __shfl_xor(tmx, msk, 64));
      float mnew = fmaxf(mrun[r], tmx);
      float fac  = __expf(mrun[r] - mnew);
      mrun[r] = mnew;
      float p0 = __expf(sacc[0][r] - mnew);
      float p1 = __expf(sacc[1][r] - mnew);
      pe[0][r] = p0; pe[1][r] = p1;
      float ts = p0 + p1;
      #pragma unroll
      for (int msk = 1; msk < 16; msk <<= 1) ts += __shfl_xor(ts, msk, 64);
      lrun[r] = lrun[r] * fac + ts;
      #pragma unroll
      for (int dt = 0; dt < 8; ++dt) oacc[dt][r] *= fac;
    }

    // ---- P -> per-wave LDS (bf16), re-layout to A-fragment ----
    #pragma unroll
    for (int jt = 0; jt < 2; ++jt)
      #pragma unroll
      for (int r = 0; r < 4; ++r)
        s_p[w][4*g + r][jt*16 + hl] = f2bf(pe[jt][r]);

    short8 pfrag = *reinterpret_cast<const short8*>(&s_p[w][hl][g*8]);

    // ---- PV: O[16q][128d] += P[16q][32j] @ V[32j][128d] ----
    #pragma unroll
    for (int dt = 0; dt < 8; ++dt){
      short8 vfr = *reinterpret_cast<const short8*>(&s_vt[dt*16 + hl][g*8]);
      oacc[dt] = __builtin_amdgcn_mfma_f32_16x16x32_bf16(pfrag, vfr, oacc[dt], 0, 0, 0);
    }
  }

  // ---- write partials (bf16) ----
  #pragma unroll
  for (int dt = 0; dt < 8; ++dt)
    #pragma unroll
    for (int r = 0; r < 4; ++r)
      pacc[((size_t)jc*8192 + q0 + w*16 + 4*g + r)*128 + dt*16 + hl] = f2bf(oacc[dt][r]);

  if (hl < 4){
    float mv = (hl==0) ? mrun[0] : (hl==1) ? mrun[1] : (hl==2) ? mrun[2] : mrun[3];
    float lv = (hl==0) ? lrun[0] : (hl==1) ? lrun[1] : (hl==2) ? lrun[2] : lrun[3];
    int q = q0 + w*16 + 4*g + hl;
    pm[jc*8192 + q] = mv;
    pl[jc*8192 + q] = lv;
  }
}

// ---- combine chunk partials + residual + halt/stack heads ----
__global__ __launch_bounds__(256, 1) void combine_kernel(
    const ushort_t* __restrict__ pacc, const float* __restrict__ pm, const float* __restrict__ pl,
    const float* __restrict__ resb,
    const float* __restrict__ halt_W, const float* __restrict__ halt_b,
    const float* __restrict__ stack_W, const float* __restrict__ stack_b,
    float* __restrict__ out)
{
  const int tid  = threadIdx.x;
  const int lane = tid & 63;
  const int w    = tid >> 6;
  const int q    = blockIdx.x * 4 + w;

  float mv[NCH], M = -3.0e38f;
  #pragma unroll
  for (int c = 0; c < NCH; ++c){ mv[c] = pm[c*8192 + q]; M = fmaxf(M, mv[c]); }
  float f[NCH]; float L = 0.f;
  #pragma unroll
  for (int c = 0; c < NCH; ++c){ f[c] = __expf(mv[c] - M); L += pl[c*8192 + q] * f[c]; }
  float invL = 1.0f / L;

  float o0 = 0.f, o1 = 0.f;
  #pragma unroll
  for (int c = 0; c < NCH; ++c){
    const ushort_t* pa = pacc + ((size_t)c*8192 + q)*128;
    o0 += bf2f(pa[lane])      * f[c];
    o1 += bf2f(pa[64 + lane]) * f[c];
  }
  o0 = o0 * invL + resb[(size_t)q*128 + lane];
  o1 = o1 * invL + resb[(size_t)q*128 + 64 + lane];
  out[(size_t)q*64 + lane] = o0;
  out[(size_t)8192*64 + (size_t)q*64 + lane] = o1;

  float ssq  = wave_sum64(o0*o0 + o1*o1);
  float invn = 1.0f / (sqrtf(ssq) + 1e-6f);
  float zn0 = o0 * invn, zn1 = o1 * invn;
  float hp = wave_sum64(zn0*halt_W[lane]        + zn1*halt_W[64 + lane]);
  float s0 = wave_sum64(zn0*stack_W[lane]       + zn1*stack_W[64 + lane]);
  float s1 = wave_sum64(zn0*stack_W[128 + lane] + zn1*stack_W[192 + lane]);
  float s2 = wave_sum64(zn0*stack_W[256 + lane] + zn1*stack_W[320 + lane]);
  if (lane == 0){
    out[1048576 + q] = hp + halt_b[0];
    out[1056768 + (size_t)q*3 + 0] = s0 + stack_b[0];
    out[1056768 + (size_t)q*3 + 1] = s1 + stack_b[1];
    out[1056768 + (size_t)q*3 + 2] = s2 + stack_b[2];
  }
}

extern "C" void kernel_launch(void* const* d_in, const int* in_sizes, int n_in,
                              void* d_out, int out_size, void* d_ws, size_t ws_size,
                              hipStream_t stream){
  const float* z_real  = (const float*)d_in[0];
  const float* z_imag  = (const float*)d_in[1];
  const float* gate_W  = (const float*)d_in[2];
  const float* gate_b  = (const float*)d_in[3];
  const float* exp_Wr  = (const float*)d_in[4];
  const float* exp_Wi  = (const float*)d_in[5];
  const float* ln_scale= (const float*)d_in[6];
  const float* ln_shift= (const float*)d_in[7];
  const float* mod_bias= (const float*)d_in[8];
  const float* q_Wr    = (const float*)d_in[9];
  const float* q_Wi    = (const float*)d_in[10];
  const float* k_Wr    = (const float*)d_in[11];
  const float* k_Wi    = (const float*)d_in[12];
  const float* v_Wr    = (const float*)d_in[13];
  const float* v_Wi    = (const float*)d_in[14];
  const float* ctx_W   = (const float*)d_in[15];
  const float* ctx_b   = (const float*)d_in[16];
  const float* res_W   = (const float*)d_in[17];
  const float* res_b   = (const float*)d_in[18];
  const float* halt_W  = (const float*)d_in[19];
  const float* halt_b  = (const float*)d_in[20];
  const float* stack_W = (const float*)d_in[21];
  const float* stack_b = (const float*)d_in[22];

  ushort_t* qbf = (ushort_t*)d_ws;
  ushort_t* kbf = qbf + (size_t)8192*128;
  ushort_t* vtb = kbf + (size_t)8192*128;        // transposed V [128][8192]
  float* resb = (float*)(vtb + (size_t)8192*128);
  ushort_t* pacc = (ushort_t*)(resb + (size_t)8192*128);
  float* pm   = (float*)(pacc + (size_t)NCH*8192*128);
  float* pl   = pm   + NCH*8192;

  prep_kernel<<<512, 256, 0, stream>>>(z_real, z_imag, gate_W, gate_b, exp_Wr, exp_Wi,
      ln_scale, ln_shift, mod_bias, q_Wr, q_Wi, k_Wr, k_Wi, v_Wr, v_Wi,
      ctx_W, ctx_b, res_W, res_b, qbf, kbf, vtb, resb);
  attn_mfma<<<128*NCH, 256, 0, stream>>>(qbf, kbf, vtb, pacc, pm, pl);
  combine_kernel<<<2048, 256, 0, stream>>>(pacc, pm, pl, resb,
      halt_W, halt_b, stack_W, stack_b, (float*)d_out);
}

// Round 4
// 160.524 us; speedup vs baseline: 7.3524x; 1.4198x over previous
//
#include <hip/hip_runtime.h>
#include <math.h>

#define EPS_F 1e-6f
#define NCH   8          // KV chunks
#define CHUNK 1024       // 8192 / NCH
#define TILES 32         // CHUNK / 32

typedef __attribute__((ext_vector_type(8))) short short8;
typedef __attribute__((ext_vector_type(4))) float f32x4;
typedef unsigned short ushort_t;
typedef unsigned int uint_t;

__device__ __forceinline__ ushort_t f2bf(float x){
  uint_t u = __float_as_uint(x);
  u += 0x7fffu + ((u >> 16) & 1u);
  return (ushort_t)(u >> 16);
}
__device__ __forceinline__ float bf2f(ushort_t u){
  return __uint_as_float(((uint_t)u) << 16);
}
__device__ __forceinline__ uint_t pack2bf(float lo, float hi){
  return (uint_t)f2bf(lo) | ((uint_t)f2bf(hi) << 16);
}

__device__ __forceinline__ float wave_sum64(float v){
  #pragma unroll
  for (int m = 32; m > 0; m >>= 1) v += __shfl_xor(v, m, 64);
  return v;
}

// Stage a 64x64 block of weights (row-major, given row stride) into LDS
// transposed with pad: s[d*65 + k] = W[k*stride + d].  256 threads.
__device__ __forceinline__ void stage64(const float* __restrict__ W, int row_stride,
                                        float* __restrict__ s, int tid){
  #pragma unroll
  for (int i = 0; i < 4; ++i){
    int g4 = tid + i * 256;
    int kk = g4 >> 4;
    int dd = (g4 & 15) * 4;
    float4 v = *reinterpret_cast<const float4*>(W + kk * row_stride + dd);
    s[(dd + 0) * 65 + kk] = v.x;
    s[(dd + 1) * 65 + kk] = v.y;
    s[(dd + 2) * 65 + kk] = v.z;
    s[(dd + 3) * 65 + kk] = v.w;
  }
}

__device__ __forceinline__ void cproj4(const float* __restrict__ sx, const float* __restrict__ sy,
                                       const float* __restrict__ w0, const float* __restrict__ w1,
                                       int g, int k, float orr[4], float oii[4]){
  #pragma unroll
  for (int j = 0; j < 4; ++j){ orr[j] = 0.f; oii[j] = 0.f; }
  #pragma unroll 4
  for (int d = 0; d < 64; ++d){
    float a = w0[d*65 + k], b = w1[d*65 + k];
    #pragma unroll
    for (int j = 0; j < 4; ++j){
      float xr = sx[(g*4+j)*68 + d];
      float xi = sy[(g*4+j)*68 + d];
      orr[j] = fmaf(xr, a, orr[j]);
      orr[j] = fmaf(-xi, b, orr[j]);
      oii[j] = fmaf(xi, a, oii[j]);
      oii[j] = fmaf(xr, b, oii[j]);
    }
  }
}

#define RA 16

__global__ __launch_bounds__(256, 1) void prep_kernel(
    const float* __restrict__ z_real, const float* __restrict__ z_imag,
    const float* __restrict__ gate_W, const float* __restrict__ gate_b,
    const float* __restrict__ exp_Wr, const float* __restrict__ exp_Wi,
    const float* __restrict__ ln_scale, const float* __restrict__ ln_shift,
    const float* __restrict__ mod_bias,
    const float* __restrict__ q_Wr, const float* __restrict__ q_Wi,
    const float* __restrict__ k_Wr, const float* __restrict__ k_Wi,
    const float* __restrict__ v_Wr, const float* __restrict__ v_Wi,
    const float* __restrict__ ctx_W, const float* __restrict__ ctx_b,
    const float* __restrict__ res_W, const float* __restrict__ res_b,
    ushort_t* __restrict__ qf, ushort_t* __restrict__ kf, ushort_t* __restrict__ vt,
    float* __restrict__ resb)
{
  const int tid = threadIdx.x;
  const int k   = tid & 63;
  const int g   = tid >> 6;
  const int row0 = blockIdx.x * RA;

  __shared__ float s_zr[RA * 68];
  __shared__ float s_zi[RA * 68];
  __shared__ float s_ar[RA * 68];
  __shared__ float s_ai[RA * 68];
  __shared__ float s_cw[RA * 132];
  __shared__ float s_gw[RA][4];
  __shared__ float s_w0[64 * 65];
  __shared__ float s_w1[64 * 65];
  __shared__ ushort_t s_tv[128][20];   // V^T staging: s_tv[d][local_row]

  {
    int r  = tid >> 4;
    int dd = (tid & 15) * 4;
    float4 a = *reinterpret_cast<const float4*>(z_real + (size_t)(row0 + r) * 64 + dd);
    float4 b = *reinterpret_cast<const float4*>(z_imag + (size_t)(row0 + r) * 64 + dd);
    *reinterpret_cast<float4*>(s_zr + r * 68 + dd) = a;
    *reinterpret_cast<float4*>(s_zi + r * 68 + dd) = b;
  }
  __syncthreads();

  {
    int r = tid >> 4;
    float lg[4];
    #pragma unroll
    for (int e = 0; e < 4; ++e){
      float acc = gate_b[e];
      #pragma unroll 8
      for (int d = 0; d < 64; ++d)
        acc += s_zr[r*68 + d] * gate_W[e*128 + d] + s_zi[r*68 + d] * gate_W[e*128 + 64 + d];
      lg[e] = acc;
    }
    float mx = fmaxf(fmaxf(lg[0], lg[1]), fmaxf(lg[2], lg[3]));
    float e0 = __expf(lg[0]-mx), e1 = __expf(lg[1]-mx), e2 = __expf(lg[2]-mx), e3 = __expf(lg[3]-mx);
    float inv = 1.0f / (e0 + e1 + e2 + e3);
    if ((tid & 15) == 0){
      s_gw[r][0] = e0*inv; s_gw[r][1] = e1*inv; s_gw[r][2] = e2*inv; s_gw[r][3] = e3*inv;
    }
  }
  __syncthreads();

  // ---- MoE experts ----
  float mr[4] = {0,0,0,0}, mi[4] = {0,0,0,0};
  for (int e = 0; e < 4; ++e){
    stage64(exp_Wr + e*4096, 64, s_w0, tid);
    stage64(exp_Wi + e*4096, 64, s_w1, tid);
    __syncthreads();
    float er[4], ei[4];
    cproj4(s_zr, s_zi, s_w0, s_w1, g, k, er, ei);
    #pragma unroll
    for (int j = 0; j < 4; ++j){
      float gwv = s_gw[g*4+j][e];
      mr[j] = fmaf(gwv, er[j], mr[j]);
      mi[j] = fmaf(gwv, ei[j], mi[j]);
    }
    __syncthreads();
  }

  { // ---- ComplexLayerNorm (ddof=1) + ModReLU ----
    float lsc = ln_scale[k], lsh = ln_shift[k], mb = mod_bias[k];
    #pragma unroll
    for (int j = 0; j < 4; ++j){
      int r = g*4 + j;
      float h   = sqrtf(mr[j]*mr[j] + mi[j]*mi[j]);
      float mag = h + EPS_F;
      float mean = wave_sum64(mag) * (1.0f/64.0f);
      float diff = mag - mean;
      float var  = wave_sum64(diff*diff) * (1.0f/63.0f);
      float nm   = diff * rsqrtf(var + EPS_F) * lsc + lsh;
      float lr, li;
      if (h > 0.0f){ float ih = 1.0f/h; lr = nm * mr[j] * ih; li = nm * mi[j] * ih; }
      else         { lr = nm; li = 0.0f; }
      float nrm = sqrtf(lr*lr + li*li) + EPS_F;
      float sf  = fmaxf(nrm + mb, 0.0f) / nrm;
      s_ar[r*68 + k] = lr * sf;
      s_ai[r*68 + k] = li * sf;
    }
  }
  __syncthreads();

  // ---- ctx gate ----
  for (int ph = 0; ph < 2; ++ph){
    stage64(ctx_W + ph*64*128,      128, s_w0, tid);
    stage64(ctx_W + ph*64*128 + 64, 128, s_w1, tid);
    __syncthreads();
    float cb = ctx_b[ph*64 + k];
    float cc[4] = {cb, cb, cb, cb};
    #pragma unroll 4
    for (int d = 0; d < 64; ++d){
      float a = s_w0[d*65 + k], b = s_w1[d*65 + k];
      #pragma unroll
      for (int j = 0; j < 4; ++j){
        cc[j] = fmaf(s_zr[(g*4+j)*68 + d], a, cc[j]);
        cc[j] = fmaf(s_zi[(g*4+j)*68 + d], b, cc[j]);
      }
    }
    #pragma unroll
    for (int j = 0; j < 4; ++j)
      s_cw[(g*4+j)*132 + ph*64 + k] = 1.0f / (1.0f + __expf(-cc[j]));
    __syncthreads();
  }

  // ---- residual projection ----
  for (int ph = 0; ph < 2; ++ph){
    stage64(res_W + ph*64*128,      128, s_w0, tid);
    stage64(res_W + ph*64*128 + 64, 128, s_w1, tid);
    __syncthreads();
    float rb = res_b[ph*64 + k];
    float cc[4] = {rb, rb, rb, rb};
    #pragma unroll 4
    for (int d = 0; d < 64; ++d){
      float a = s_w0[d*65 + k], b = s_w1[d*65 + k];
      #pragma unroll
      for (int j = 0; j < 4; ++j){
        cc[j] = fmaf(s_zr[(g*4+j)*68 + d], a, cc[j]);
        cc[j] = fmaf(s_zi[(g*4+j)*68 + d], b, cc[j]);
      }
    }
    #pragma unroll
    for (int j = 0; j < 4; ++j)
      resb[(size_t)(row0 + g*4 + j)*128 + ph*64 + k] = 0.1f * cc[j];
    __syncthreads();
  }

  { // ---- Q projection (gated, ATTN_SCALE folded, bf16 out) ----
    stage64(q_Wr, 64, s_w0, tid);
    stage64(q_Wi, 64, s_w1, tid);
    __syncthreads();
    float orr[4], oii[4];
    cproj4(s_ar, s_ai, s_w0, s_w1, g, k, orr, oii);
    #pragma unroll
    for (int j = 0; j < 4; ++j){
      int r = g*4 + j; size_t row = row0 + r;
      qf[row*128 + k]      = f2bf(orr[j] * s_cw[r*132 + k]      * 0.125f);
      qf[row*128 + 64 + k] = f2bf(oii[j] * s_cw[r*132 + 64 + k] * 0.125f);
    }
    __syncthreads();
  }
  { // ---- K projection (bf16 out) ----
    stage64(k_Wr, 64, s_w0, tid);
    stage64(k_Wi, 64, s_w1, tid);
    __syncthreads();
    float orr[4], oii[4];
    cproj4(s_ar, s_ai, s_w0, s_w1, g, k, orr, oii);
    #pragma unroll
    for (int j = 0; j < 4; ++j){
      size_t row = row0 + g*4 + j;
      kf[row*128 + k]      = f2bf(orr[j]);
      kf[row*128 + 64 + k] = f2bf(oii[j]);
    }
    __syncthreads();
  }
  { // ---- V projection (bf16, TRANSPOSED to global vt[128][8192]) ----
    stage64(v_Wr, 64, s_w0, tid);
    stage64(v_Wi, 64, s_w1, tid);
    __syncthreads();
    float orr[4], oii[4];
    cproj4(s_ar, s_ai, s_w0, s_w1, g, k, orr, oii);
    #pragma unroll
    for (int j = 0; j < 4; ++j){
      s_tv[k]     [g*4 + j] = f2bf(orr[j]);
      s_tv[64 + k][g*4 + j] = f2bf(oii[j]);
    }
    __syncthreads();
    // write out: thread -> (d = tid>>1, half = tid&1), 16 bytes each
    int d = tid >> 1, half = tid & 1;
    uint2 a = *reinterpret_cast<const uint2*>(&s_tv[d][half*8]);
    uint2 b = *reinterpret_cast<const uint2*>(&s_tv[d][half*8 + 4]);
    uint4 o; o.x = a.x; o.y = a.y; o.z = b.x; o.w = b.y;
    *reinterpret_cast<uint4*>(vt + (size_t)d*8192 + row0 + half*8) = o;
  }
}

// ---- MFMA flash attention, swapped operands: 128 q-blocks x NCH key-chunks ----
// Block: 4 waves, each wave owns 16 query rows (q = lane&15).
// S^T = mfma(K, Q): lane holds one q-row's 32 scores -> softmax nearly lane-local.
// O^T = mfma(V^T, P^T) accumulated per d-tile.
__global__ __launch_bounds__(256, 4) void attn_mfma(
    const ushort_t* __restrict__ qf, const ushort_t* __restrict__ kf, const ushort_t* __restrict__ vt,
    ushort_t* __restrict__ pacc, float* __restrict__ pm, float* __restrict__ pl)
{
  const int tid  = threadIdx.x;
  const int lane = tid & 63;
  const int w    = tid >> 6;
  const int g    = lane >> 4;      // 0..3 (k-slice owner)
  const int hl   = lane & 15;      // q within wave tile
  const int qb   = blockIdx.x & 127;
  const int jc   = blockIdx.x >> 7;
  const int q0   = qb * 64;
  const int qr   = q0 + w*16 + hl; // this lane's q row

  __shared__ ushort_t s_k[32][136];    // K tile row-major (pad 136)
  __shared__ ushort_t s_vt[128][40];   // V^T tile: s_vt[d][j] (pad 40)
  __shared__ uint_t   s_p32[4][16][20];// per-wave P (bf16x2), pitch 20 u32 (16B-aligned rows)

  // staging address precompute
  const int kjj0 = tid >> 4;            // K: row within tile
  const int kkk  = (tid & 15) * 8;      // K: col (8 bf16 = 16B)
  const int vd0  = tid >> 2;            // V: d row
  const int vjo  = (tid & 3) * 8;       // V: j within tile

  // Q as B-operand: lane holds Q[qr][kt*32 + g*8 + e]
  short8 qfrag[4];
  #pragma unroll
  for (int kt = 0; kt < 4; ++kt)
    qfrag[kt] = *reinterpret_cast<const short8*>(qf + (size_t)qr*128 + kt*32 + g*8);

  f32x4 oacc[8];   // O^T: oacc[dt][r] = O[q=hl][d = dt*16 + 4g + r]
  #pragma unroll
  for (int dt = 0; dt < 8; ++dt) oacc[dt] = (f32x4){0.f, 0.f, 0.f, 0.f};
  float mrun = -3.0e38f, lrun = 0.f;

  const int jstart = jc * CHUNK;

  for (int t = 0; t < TILES; ++t){
    const int jb = jstart + t*32;
    __syncthreads();   // previous tile's compute done
    #pragma unroll
    for (int i = 0; i < 2; ++i){
      *reinterpret_cast<uint4*>(&s_k[kjj0 + i*16][kkk]) =
          *reinterpret_cast<const uint4*>(kf + (size_t)(jb + kjj0 + i*16)*128 + kkk);
      *reinterpret_cast<uint4*>(&s_vt[vd0 + i*64][vjo]) =
          *reinterpret_cast<const uint4*>(vt + (size_t)(vd0 + i*64)*8192 + jb + vjo);
    }
    __syncthreads();

    // ---- QK^T (swapped): S^T tile. sacc[jt][r] = S[q=hl][j = jt*16 + 4g + r]
    f32x4 sacc[2];
    #pragma unroll
    for (int jt = 0; jt < 2; ++jt){
      sacc[jt] = (f32x4){0.f, 0.f, 0.f, 0.f};
      #pragma unroll
      for (int kt = 0; kt < 4; ++kt){
        short8 kfr = *reinterpret_cast<const short8*>(&s_k[jt*16 + hl][kt*32 + g*8]);
        sacc[jt] = __builtin_amdgcn_mfma_f32_16x16x32_bf16(kfr, qfrag[kt], sacc[jt], 0, 0, 0);
      }
    }

    // ---- per-lane online softmax (q = hl), cross-g reduction only ----
    float t0 = fmaxf(fmaxf(fmaxf(sacc[0][0], sacc[0][1]), fmaxf(sacc[0][2], sacc[0][3])),
                     fmaxf(fmaxf(sacc[1][0], sacc[1][1]), fmaxf(sacc[1][2], sacc[1][3])));
    t0 = fmaxf(t0, __shfl_xor(t0, 16, 64));
    t0 = fmaxf(t0, __shfl_xor(t0, 32, 64));
    float mnew = fmaxf(mrun, t0);
    float fac  = __expf(mrun - mnew);
    float pe[2][4];
    float ps = 0.f;
    #pragma unroll
    for (int jt = 0; jt < 2; ++jt)
      #pragma unroll
      for (int r = 0; r < 4; ++r){
        float p = __expf(sacc[jt][r] - mnew);
        pe[jt][r] = p;
        ps += p;
      }
    ps += __shfl_xor(ps, 16, 64);
    ps += __shfl_xor(ps, 32, 64);
    lrun = lrun * fac + ps;
    mrun = mnew;
    #pragma unroll
    for (int dt = 0; dt < 8; ++dt){
      oacc[dt][0] *= fac; oacc[dt][1] *= fac; oacc[dt][2] *= fac; oacc[dt][3] *= fac;
    }

    // ---- P^T -> per-wave LDS (packed bf16x2), re-read as PV B-fragment ----
    {
      uint2 w0; w0.x = pack2bf(pe[0][0], pe[0][1]); w0.y = pack2bf(pe[0][2], pe[0][3]);
      uint2 w1; w1.x = pack2bf(pe[1][0], pe[1][1]); w1.y = pack2bf(pe[1][2], pe[1][3]);
      *reinterpret_cast<uint2*>(&s_p32[w][hl][2*g])     = w0;   // j = 4g..4g+3
      *reinterpret_cast<uint2*>(&s_p32[w][hl][8 + 2*g]) = w1;   // j = 16+4g..16+4g+3
    }
    short8 pfrag = *reinterpret_cast<const short8*>(&s_p32[w][hl][4*g]); // j = 8g..8g+7

    // ---- PV (swapped): O^T[d-tile][q] += V^T @ P^T ----
    #pragma unroll
    for (int dt = 0; dt < 8; ++dt){
      short8 vfr = *reinterpret_cast<const short8*>(&s_vt[dt*16 + hl][g*8]);
      oacc[dt] = __builtin_amdgcn_mfma_f32_16x16x32_bf16(vfr, pfrag, oacc[dt], 0, 0, 0);
    }
  }

  // ---- write partials (bf16, pair-packed 8B stores) ----
  #pragma unroll
  for (int dt = 0; dt < 8; ++dt){
    uint2 o;
    o.x = pack2bf(oacc[dt][0], oacc[dt][1]);
    o.y = pack2bf(oacc[dt][2], oacc[dt][3]);
    *reinterpret_cast<uint2*>(pacc + ((size_t)jc*8192 + qr)*128 + dt*16 + 4*g) = o;
  }
  if (g == 0){
    pm[jc*8192 + qr] = mrun;
    pl[jc*8192 + qr] = lrun;
  }
}

// ---- combine chunk partials + residual + halt/stack heads ----
__global__ __launch_bounds__(256, 1) void combine_kernel(
    const ushort_t* __restrict__ pacc, const float* __restrict__ pm, const float* __restrict__ pl,
    const float* __restrict__ resb,
    const float* __restrict__ halt_W, const float* __restrict__ halt_b,
    const float* __restrict__ stack_W, const float* __restrict__ stack_b,
    float* __restrict__ out)
{
  const int tid  = threadIdx.x;
  const int lane = tid & 63;
  const int w    = tid >> 6;
  const int q    = blockIdx.x * 4 + w;

  float mv[NCH], M = -3.0e38f;
  #pragma unroll
  for (int c = 0; c < NCH; ++c){ mv[c] = pm[c*8192 + q]; M = fmaxf(M, mv[c]); }
  float f[NCH]; float L = 0.f;
  #pragma unroll
  for (int c = 0; c < NCH; ++c){ f[c] = __expf(mv[c] - M); L += pl[c*8192 + q] * f[c]; }
  float invL = 1.0f / L;

  float o0 = 0.f, o1 = 0.f;
  #pragma unroll
  for (int c = 0; c < NCH; ++c){
    const ushort_t* pa = pacc + ((size_t)c*8192 + q)*128;
    o0 += bf2f(pa[lane])      * f[c];
    o1 += bf2f(pa[64 + lane]) * f[c];
  }
  o0 = o0 * invL + resb[(size_t)q*128 + lane];
  o1 = o1 * invL + resb[(size_t)q*128 + 64 + lane];
  out[(size_t)q*64 + lane] = o0;
  out[(size_t)8192*64 + (size_t)q*64 + lane] = o1;

  float ssq  = wave_sum64(o0*o0 + o1*o1);
  float invn = 1.0f / (sqrtf(ssq) + 1e-6f);
  float zn0 = o0 * invn, zn1 = o1 * invn;
  float hp = wave_sum64(zn0*halt_W[lane]        + zn1*halt_W[64 + lane]);
  float s0 = wave_sum64(zn0*stack_W[lane]       + zn1*stack_W[64 + lane]);
  float s1 = wave_sum64(zn0*stack_W[128 + lane] + zn1*stack_W[192 + lane]);
  float s2 = wave_sum64(zn0*stack_W[256 + lane] + zn1*stack_W[320 + lane]);
  if (lane == 0){
    out[1048576 + q] = hp + halt_b[0];
    out[1056768 + (size_t)q*3 + 0] = s0 + stack_b[0];
    out[1056768 + (size_t)q*3 + 1] = s1 + stack_b[1];
    out[1056768 + (size_t)q*3 + 2] = s2 + stack_b[2];
  }
}

extern "C" void kernel_launch(void* const* d_in, const int* in_sizes, int n_in,
                              void* d_out, int out_size, void* d_ws, size_t ws_size,
                              hipStream_t stream){
  const float* z_real  = (const float*)d_in[0];
  const float* z_imag  = (const float*)d_in[1];
  const float* gate_W  = (const float*)d_in[2];
  const float* gate_b  = (const float*)d_in[3];
  const float* exp_Wr  = (const float*)d_in[4];
  const float* exp_Wi  = (const float*)d_in[5];
  const float* ln_scale= (const float*)d_in[6];
  const float* ln_shift= (const float*)d_in[7];
  const float* mod_bias= (const float*)d_in[8];
  const float* q_Wr    = (const float*)d_in[9];
  const float* q_Wi    = (const float*)d_in[10];
  const float* k_Wr    = (const float*)d_in[11];
  const float* k_Wi    = (const float*)d_in[12];
  const float* v_Wr    = (const float*)d_in[13];
  const float* v_Wi    = (const float*)d_in[14];
  const float* ctx_W   = (const float*)d_in[15];
  const float* ctx_b   = (const float*)d_in[16];
  const float* res_W   = (const float*)d_in[17];
  const float* res_b   = (const float*)d_in[18];
  const float* halt_W  = (const float*)d_in[19];
  const float* halt_b  = (const float*)d_in[20];
  const float* stack_W = (const float*)d_in[21];
  const float* stack_b = (const float*)d_in[22];

  ushort_t* qbf = (ushort_t*)d_ws;
  ushort_t* kbf = qbf + (size_t)8192*128;
  ushort_t* vtb = kbf + (size_t)8192*128;        // transposed V [128][8192]
  float* resb = (float*)(vtb + (size_t)8192*128);
  ushort_t* pacc = (ushort_t*)(resb + (size_t)8192*128);
  float* pm   = (float*)(pacc + (size_t)NCH*8192*128);
  float* pl   = pm   + NCH*8192;

  prep_kernel<<<512, 256, 0, stream>>>(z_real, z_imag, gate_W, gate_b, exp_Wr, exp_Wi,
      ln_scale, ln_shift, mod_bias, q_Wr, q_Wi, k_Wr, k_Wi, v_Wr, v_Wi,
      ctx_W, ctx_b, res_W, res_b, qbf, kbf, vtb, resb);
  attn_mfma<<<128*NCH, 256, 0, stream>>>(qbf, kbf, vtb, pacc, pm, pl);
  combine_kernel<<<2048, 256, 0, stream>>>(pacc, pm, pl, resb,
      halt_W, halt_b, stack_W, stack_b, (float*)d_out);
}